// Round 15
// baseline (75.734 us; speedup 1.0000x reference)
//
#include <hip/hip_runtime.h>
#include <hip/hip_bf16.h>
#include <math.h>

// Problem dims (fixed by reference)
constexpr int B_ = 128, T_ = 512, I_ = 1024, H_ = 2048, O_ = 512;
#define BETA 0.9f

// ws float layout: w[512] | y[B*I] | Z[B*H] | WtI bf16[H][I] | WtO bf16[O][H]
constexpr int WOFF  = 0;
constexpr int YOFF  = 512;
constexpr int ZOFF  = YOFF + B_ * I_;           // 131584
constexpr int WTI_F = ZOFF + B_ * H_;           // 393728 (float idx)
constexpr int WTO_F = WTI_F + (H_ * I_) / 2;    // + 2M ushorts = 1M floats

typedef __attribute__((ext_vector_type(4))) short short4v;   // 4 bf16
typedef __attribute__((ext_vector_type(8))) short short8v;   // 8 bf16 (4 VGPR)
typedef __attribute__((ext_vector_type(4))) float float4v;   // 4 f32

__device__ inline ushort f2bf(float f) {   // f32->bf16 RNE (R4/R7-proven)
    union { float f; unsigned u; } c; c.f = f;
    return (ushort)((c.u + 0x7FFF + ((c.u >> 16) & 1)) >> 16);
}

// init grid segmentation
constexpr int INIT_BASE = (512 + B_ * I_ + B_ * H_ + B_ * O_ + 255) / 256;  // 1794
constexpr int TI_TILES  = (I_ / 64) * (H_ / 64);   // 512
constexpr int TO_TILES  = (H_ / 64) * (O_ / 64);   // 256

// ---------------------------------------------------------------------------
// 64x64 tile transpose+convert: src f32 [K][N] row-major -> dst bf16 [N][K]
// ---------------------------------------------------------------------------
__device__ inline void transpose_tile(const float* __restrict__ src,
                                      ushort* __restrict__ dst,
                                      int K, int N, int tk, int tn,
                                      ushort (*tile)[72], int tid) {
    const int k0 = tk * 64, n0 = tn * 64;
#pragma unroll
    for (int rep = 0; rep < 4; ++rep) {
        const int kr = rep * 16 + (tid >> 4);
        const int nc = (tid & 15) * 4;
        float4v v = *(const float4v*)(src + (size_t)(k0 + kr) * N + n0 + nc);
        tile[nc + 0][kr] = f2bf(v.x);
        tile[nc + 1][kr] = f2bf(v.y);
        tile[nc + 2][kr] = f2bf(v.z);
        tile[nc + 3][kr] = f2bf(v.w);
    }
    __syncthreads();
    const int nr = tid >> 2, kc = (tid & 3) * 16;
    ushort* dp = dst + (size_t)(n0 + nr) * K + k0 + kc;
    *(short8v*)dp       = *(const short8v*)&tile[nr][kc];
    *(short8v*)(dp + 8) = *(const short8v*)&tile[nr][kc + 8];
}

// ---------------------------------------------------------------------------
// Kernel 1: R9 init (w table, y zero, Z/out bias) + weight transpose-convert
// ---------------------------------------------------------------------------
__global__ __launch_bounds__(256) void init_kernel(float* __restrict__ ws,
                                                   const float* __restrict__ b_in,
                                                   const float* __restrict__ b_out,
                                                   float* __restrict__ out, float wsum,
                                                   const float* __restrict__ Wi,
                                                   const float* __restrict__ Wo) {
    __shared__ __align__(16) ushort tile[64][72];
    const int bid = blockIdx.x, tid = threadIdx.x;
    if (bid < INIT_BASE) {
        const int idx = bid * 256 + tid;
        if (idx < 512) {
            ws[idx] = (1.0f - powf(BETA, (float)(T_ - idx))) * (1.0f / (1.0f - BETA));
        } else if (idx < ZOFF) {
            ws[idx] = 0.0f;                                 // y accumulator
        } else if (idx < WTI_F) {
            ws[idx] = wsum * b_in[(idx - ZOFF) & (H_ - 1)]; // Z bias init
        } else {
            const int j = idx - WTI_F;
            if (j < B_ * O_) out[j] = (float)T_ * b_out[j & (O_ - 1)];
        }
    } else if (bid < INIT_BASE + TI_TILES) {
        const int id = bid - INIT_BASE;                     // W_in: K=I_, N=H_
        transpose_tile(Wi, (ushort*)(ws + WTI_F), I_, H_, id >> 5, id & 31, tile, tid);
    } else {
        const int id = bid - INIT_BASE - TI_TILES;          // W_out: K=H_, N=O_
        transpose_tile(Wo, (ushort*)(ws + WTO_F), H_, O_, id >> 3, id & 7, tile, tid);
    }
}

// ---------------------------------------------------------------------------
// Kernel 2 (R9-exact): y[b,i] += sum_{t in chunk} w[t] * x[b,t,i]
// TCH=128 -> 512 blocks, plain cached float4 loads, 4-way atomics.
// ---------------------------------------------------------------------------
constexpr int TCH = 128;
__global__ __launch_bounds__(256) void wreduce_kernel(const float* __restrict__ x,
                                                      float* __restrict__ ws) {
    __shared__ float wl[TCH];
    const int b  = blockIdx.x >> 2;
    const int tc = blockIdx.x & 3;
    const int t0 = tc * TCH;
    if (threadIdx.x < TCH) wl[threadIdx.x] = ws[WOFF + t0 + threadIdx.x];
    __syncthreads();

    const int i = threadIdx.x * 4;
    const float* xp = x + (size_t)b * T_ * I_ + (size_t)t0 * I_ + i;
    float4v acc = {0.f, 0.f, 0.f, 0.f};
#pragma unroll 4
    for (int tb = 0; tb < TCH; tb += 8) {
        float4v v[8];
#pragma unroll
        for (int j = 0; j < 8; ++j)
            v[j] = *(const float4v*)(xp + (size_t)(tb + j) * I_);
#pragma unroll
        for (int j = 0; j < 8; ++j) {
            const float wt = wl[tb + j];
            acc.x += wt * v[j].x; acc.y += wt * v[j].y;
            acc.z += wt * v[j].z; acc.w += wt * v[j].w;
        }
    }
    float* yp = ws + YOFF + b * I_ + i;
    atomicAdd(yp + 0, acc.x);
    atomicAdd(yp + 1, acc.y);
    atomicAdd(yp + 2, acc.z);
    atomicAdd(yp + 3, acc.w);
}

// ---------------------------------------------------------------------------
// Kernel 3/4: C[128,N] += A[128,K] @ Wt^T, Wt = bf16 [N][K] (pre-transposed).
// BK=64 -> 16 MFMA per barrier-pair (was 8), B staging = pure vector copies.
// Builtin 16x16x32 bf16 MFMA (hazard-modeled), f32 atomic epilogue (proven).
// grid = (N/64, K/KCH); trip counts: mm1=2, mm2=1.
// ---------------------------------------------------------------------------
template <int KGLOB, int NGLOB, int KCH>
__global__ __launch_bounds__(256) void mm128T(const float* __restrict__ A,
                                              const ushort* __restrict__ Wt,
                                              float* __restrict__ C) {
    constexpr int BN = 64, BK = 64, PAD = 8;
    __shared__ __align__(16) ushort As[128][BK + PAD];  // [row][k] 19 KB
    __shared__ __align__(16) ushort Bs[BN][BK + PAD];   // [n][k]   9 KB

    const int n0    = blockIdx.x * BN;
    const int kbase = blockIdx.y * KCH;
    const int tid   = threadIdx.x;
    const int lane  = tid & 63;
    const int w     = tid >> 6;
    const int lo    = lane & 15;
    const int hi    = lane >> 4;

    float4v acc[2][4];
#pragma unroll
    for (int mf = 0; mf < 2; ++mf)
#pragma unroll
        for (int nf = 0; nf < 4; ++nf) acc[mf][nf] = (float4v){0.f, 0.f, 0.f, 0.f};

    for (int k0 = kbase; k0 < kbase + KCH; k0 += BK) {
        {   // stage A 128x64: row=tid>>1, k-half=(tid&1)*32, f32->bf16
            const int row = tid >> 1;
            const int kh  = (tid & 1) * 32;
            const float* ap = A + (size_t)row * KGLOB + k0 + kh;
#pragma unroll
            for (int j = 0; j < 8; ++j) {
                float4v v = *(const float4v*)(ap + 4 * j);
                short4v s;
                s[0] = (short)f2bf(v.x); s[1] = (short)f2bf(v.y);
                s[2] = (short)f2bf(v.z); s[3] = (short)f2bf(v.w);
                *(short4v*)&As[row][kh + 4 * j] = s;
            }
        }
        {   // stage B 64x64 from bf16 [n][k]: n=tid>>2, k-quarter=(tid&3)*16
            const int n  = tid >> 2;
            const int kq = (tid & 3) * 16;
            const ushort* wp = Wt + (size_t)(n0 + n) * KGLOB + k0 + kq;
            *(short8v*)&Bs[n][kq]     = *(const short8v*)wp;
            *(short8v*)&Bs[n][kq + 8] = *(const short8v*)(wp + 8);
        }
        __syncthreads();
#pragma unroll
        for (int ks = 0; ks < 2; ++ks) {
            const int kk = ks * 32 + hi * 8;
            short8v a[2], bv[4];
#pragma unroll
            for (int mf = 0; mf < 2; ++mf)
                a[mf] = *(const short8v*)&As[w * 32 + mf * 16 + lo][kk];
#pragma unroll
            for (int nf = 0; nf < 4; ++nf)
                bv[nf] = *(const short8v*)&Bs[nf * 16 + lo][kk];
#pragma unroll
            for (int mf = 0; mf < 2; ++mf)
#pragma unroll
                for (int nf = 0; nf < 4; ++nf)
                    acc[mf][nf] = __builtin_amdgcn_mfma_f32_16x16x32_bf16(
                        a[mf], bv[nf], acc[mf][nf], 0, 0, 0);
        }
        __syncthreads();
    }
    // epilogue: split-K atomic accumulate (C pre-initialized with bias)
#pragma unroll
    for (int mf = 0; mf < 2; ++mf)
#pragma unroll
        for (int nf = 0; nf < 4; ++nf)
#pragma unroll
            for (int i = 0; i < 4; ++i) {
                const int row = w * 32 + mf * 16 + hi * 4 + i;
                const int col = n0 + nf * 16 + lo;
                atomicAdd(&C[(size_t)row * NGLOB + col], acc[mf][nf][i]);
            }
}

// ---------------------------------------------------------------------------
extern "C" void kernel_launch(void* const* d_in, const int* in_sizes, int n_in,
                              void* d_out, int out_size, void* d_ws, size_t ws_size,
                              hipStream_t stream) {
    const float* x     = (const float*)d_in[0];
    const float* W_in  = (const float*)d_in[1];
    const float* b_in  = (const float*)d_in[2];
    const float* W_out = (const float*)d_in[3];
    const float* b_out = (const float*)d_in[4];
    float* out = (float*)d_out;
    float* ws  = (float*)d_ws;

    // wsum = sum_t (1-beta^(T-t))/(1-beta), exact in double on host
    const double beta = 0.9;
    const double bT = pow(beta, (double)T_);
    const float wsum = (float)(((double)T_ - beta * (1.0 - bT) / (1.0 - beta)) / (1.0 - beta));

    init_kernel<<<INIT_BASE + TI_TILES + TO_TILES, 256, 0, stream>>>(
        ws, b_in, b_out, out, wsum, W_in, W_out);

    wreduce_kernel<<<B_ * (T_ / TCH), 256, 0, stream>>>(x, ws);

    // Z = y @ W_in : KCH=128 -> 8 splits x 32 nb = 256 blocks, 2 iters each
    mm128T<I_, H_, 128><<<dim3(H_ / 64, I_ / 128), 256, 0, stream>>>(
        ws + YOFF, (const ushort*)(ws + WTI_F), ws + ZOFF);

    // out = Z @ W_out : KCH=64 -> 32 splits x 8 nb = 256 blocks, 1 iter each
    mm128T<H_, O_, 64><<<dim3(O_ / 64, H_ / 64), 256, 0, stream>>>(
        ws + ZOFF, (const ushort*)(ws + WTO_F), out);
}